// Round 4
// baseline (297.787 us; speedup 1.0000x reference)
//
#include <hip/hip_runtime.h>
#include <hip/hip_bf16.h>
#include <math.h>

typedef __attribute__((ext_vector_type(4))) float f32x4;
typedef __attribute__((ext_vector_type(8))) short bf16x8;
typedef __attribute__((ext_vector_type(4))) short bf16x4;
typedef unsigned short u16;
typedef unsigned int u32;

// T=2048, D=2048, NH=32, NKV=8, HD=64, G=4

__device__ __forceinline__ u16 f2bf(float f) {
    return __builtin_bit_cast(u16, __float2bfloat16(f));   // native v_cvt on gfx950
}
__device__ __forceinline__ float bf2f(u16 h) {
    return __builtin_bit_cast(float, ((u32)h) << 16);
}

// async global->LDS, 16B per lane; dest is wave-uniform base + lane*16
#define GLL16(gsrc, ldst) __builtin_amdgcn_global_load_lds( \
    (const __attribute__((address_space(1))) u32*)(gsrc),   \
    (__attribute__((address_space(3))) u32*)(ldst), 16, 0, 0)

// ---------------- f32 -> bf16 convert (x) ----------------
__global__ void k_cvt(const float* __restrict__ in, u16* __restrict__ out, int n) {
    int i = blockIdx.x * blockDim.x + threadIdx.x;
    int base = i * 4;
    if (base < n) {
        float4 v = *(const float4*)(in + base);
        ushort4 o;
        o.x = f2bf(v.x); o.y = f2bf(v.y); o.z = f2bf(v.z); o.w = f2bf(v.w);
        *(ushort4*)(out + base) = o;
    }
}

// ------------- transpose + convert: in [R][C] f32 -> out [C][R] bf16 -------------
__global__ void k_tconv(const float* __restrict__ in, u16* __restrict__ out, int R, int C) {
    __shared__ float tile[32][33];
    int c0 = blockIdx.x * 32, r0 = blockIdx.y * 32;
    int tx = threadIdx.x, ty = threadIdx.y;        // (32,8)
    #pragma unroll
    for (int i = 0; i < 4; ++i)
        tile[ty + i * 8][tx] = in[(size_t)(r0 + ty + i * 8) * C + c0 + tx];
    __syncthreads();
    #pragma unroll
    for (int i = 0; i < 4; ++i)
        out[(size_t)(c0 + ty + i * 8) * R + r0 + tx] = f2bf(tile[tx][ty + i * 8]);
}

// ------------- bf16 transpose: in [R][stride, C cols] -> out [C][R] -------------
__global__ void k_tbf16(const u16* __restrict__ in, int inStride, u16* __restrict__ out, int R, int C) {
    __shared__ u16 tile[32][34];
    int c0 = blockIdx.x * 32, r0 = blockIdx.y * 32;
    int tx = threadIdx.x, ty = threadIdx.y;        // (32,8)
    #pragma unroll
    for (int i = 0; i < 4; ++i)
        tile[ty + i * 8][tx] = in[(size_t)(r0 + ty + i * 8) * inStride + c0 + tx];
    __syncthreads();
    #pragma unroll
    for (int i = 0; i < 4; ++i)
        out[(size_t)(c0 + ty + i * 8) * R + r0 + tx] = tile[tx][ty + i * 8];
}

// ------------- RoPE in-place on QKV; Q gets 1/sqrt(HD)=0.125 folded in; fills padf -------------
__global__ void k_rope(u16* QKV,
                       const float* __restrict__ cosp, const float* __restrict__ sinp,
                       const int* __restrict__ maskp, float* __restrict__ padf) {
    int t = blockIdx.y;
    int idx = blockIdx.x * blockDim.x + threadIdx.x;   // 0..1279 ; 40 heads * 32 pairs
    if (blockIdx.x == 0 && threadIdx.x == 0)
        padf[t] = maskp[t] ? 0.0f : -3.4028235e38f;
    int h = idx >> 5;
    int j = idx & 31;
    u16* base = QKV + (size_t)t * 3072 + (h < 32 ? h * 64 : 2048 + (h - 32) * 64);
    float sc = (h < 32) ? 0.125f : 1.0f;
    float q1 = bf2f(base[j]);
    float q2 = bf2f(base[j + 32]);
    float c1 = cosp[t * 64 + j],      s1 = sinp[t * 64 + j];
    float c2 = cosp[t * 64 + j + 32], s2 = sinp[t * 64 + j + 32];
    base[j]      = f2bf((q1 * c1 - q2 * s1) * sc);
    base[j + 32] = f2bf((q2 * c2 + q1 * s2) * sc);
}

// ------------- bf16 GEMM: C[M][N] = A[M][K] * Bt[N][K]^T -------------
// 128x128 tile, BK=32, 512 threads (8 waves: 2 row x 4 col, wave tile 64x32),
// double-buffered LDS, stage-next-before-compute (2-phase), 1 barrier/iter.
template<int OUTF32>
__global__ __launch_bounds__(512) void k_gemm(const u16* __restrict__ A, int lda,
                                              const u16* __restrict__ Bt,
                                              void* __restrict__ Cv,
                                              int M, int N, int K) {
    __shared__ u16 As[2][128 * 32];
    __shared__ u16 Bs[2][128 * 32];
    const int tid = threadIdx.x;
    const int w = tid >> 6, lane = tid & 63;
    const int wr = w & 1, wc = w >> 1;             // wr 0..1 (64 rows), wc 0..3 (32 cols)
    const int g = lane >> 4, l15 = lane & 15;
    const int m0 = blockIdx.y * 128, n0 = blockIdx.x * 128;

    f32x4 acc[4][2] = {};

    const int p = tid;
    const int r = p >> 2, kc = (p & 3) ^ (r & 3);
    const u16* ga = A + (size_t)(m0 + r) * lda + kc * 8;
    const u16* gb = Bt + (size_t)(n0 + r) * K + kc * 8;
    u16* la = &As[0][0] + (size_t)p * 8;
    u16* lb = &Bs[0][0] + (size_t)p * 8;
    const size_t bufoff = 128 * 32;

    GLL16(ga, la);
    GLL16(gb, lb);
    __syncthreads();
    int buf = 0;

    for (int k0 = 0; k0 < K; k0 += 32) {
        int kn = k0 + 32;
        if (kn < K) {                                // prefetch next K-tile into other buf
            GLL16(ga + kn, la + (buf ^ 1) * bufoff);
            GLL16(gb + kn, lb + (buf ^ 1) * bufoff);
        }
        bf16x8 af[4], bfr[2];
        #pragma unroll
        for (int mt = 0; mt < 4; ++mt) {
            int row = wr * 64 + mt * 16 + l15;
            af[mt] = *(const bf16x8*)&As[buf][row * 32 + ((g ^ (row & 3)) << 3)];
        }
        #pragma unroll
        for (int nt = 0; nt < 2; ++nt) {
            int rowb = wc * 32 + nt * 16 + l15;
            bfr[nt] = *(const bf16x8*)&Bs[buf][rowb * 32 + ((g ^ (rowb & 3)) << 3)];
        }
        #pragma unroll
        for (int mt = 0; mt < 4; ++mt)
            #pragma unroll
            for (int nt = 0; nt < 2; ++nt)
                acc[mt][nt] = __builtin_amdgcn_mfma_f32_16x16x32_bf16(af[mt], bfr[nt], acc[mt][nt], 0, 0, 0);
        __syncthreads();
        buf ^= 1;
    }
    #pragma unroll
    for (int mt = 0; mt < 4; ++mt) {
        #pragma unroll
        for (int nt = 0; nt < 2; ++nt) {
            int mrow = m0 + wr * 64 + mt * 16 + g * 4;
            int ncol = n0 + wc * 32 + nt * 16 + l15;
            #pragma unroll
            for (int rr = 0; rr < 4; ++rr) {
                float v = acc[mt][nt][rr];
                if (OUTF32) ((float*)Cv)[(size_t)(mrow + rr) * N + ncol] = v;
                else        ((u16*)Cv)[(size_t)(mrow + rr) * N + ncol] = f2bf(v);
            }
        }
    }
}

// ------------- PV MFMA: prefer 16x16x16 bf16; fallback = zero-padded 16x16x32 -------------
#if defined(__has_builtin)
#if __has_builtin(__builtin_amdgcn_mfma_f32_16x16x16bf16_1k)
#define HAVE_1K 1
#endif
#endif
__device__ __forceinline__ f32x4 pv_mfma(bf16x4 a, bf16x4 b, f32x4 c) {
#ifdef HAVE_1K
    return __builtin_amdgcn_mfma_f32_16x16x16bf16_1k(a, b, c, 0, 0, 0);
#else
    bf16x8 a8 = {a[0], a[1], a[2], a[3], (short)0, (short)0, (short)0, (short)0};
    bf16x8 b8 = {b[0], b[1], b[2], b[3], (short)0, (short)0, (short)0, (short)0};
    return __builtin_amdgcn_mfma_f32_16x16x32_bf16(a8, b8, c, 0, 0, 0);
#endif
}

// ------------- flash attention, barrier-free, direct-from-L2 -------------
// Block = 4 INDEPENDENT waves (no LDS, no __syncthreads), one Q-head each, sharing
// one KV-head's K/V (L1/L2 reuse). Each wave: 32 q-rows as 2 16-row q-tiles.
// K frags loaded straight from QKV (16 full 64B lines per bf16x8 instr);
// V frags from Vt. Swapped layout: S^T = K*Q^T so softmax is lane-local and
// P^T is directly the PV B-fragment. Causal mask only in the tail (diagonal) tile.
__global__ __launch_bounds__(256) void k_attn(const u16* __restrict__ QKV,
                                              const u16* __restrict__ VtG,
                                              const float* __restrict__ padf,
                                              u16* __restrict__ Ob) {
    const int qt32 = 63 - (int)blockIdx.x;         // longest blocks first
    const int kvh = blockIdx.y;
    const int w = threadIdx.x >> 6, lane = threadIdx.x & 63;
    const int g = lane >> 4, l15 = lane & 15;
    const int h = kvh * 4 + w;
    const int q0 = qt32 * 32;
    const int iters = (qt32 >> 1) + 1;

    // Q fragments for both q-tiles (pre-scaled by 0.125 in k_rope)
    bf16x8 qf[2][2];
    #pragma unroll
    for (int qt = 0; qt < 2; ++qt)
        #pragma unroll
        for (int kc = 0; kc < 2; ++kc)
            qf[qt][kc] = *(const bf16x8*)(QKV + (size_t)(q0 + qt * 16 + l15) * 3072 + h * 64 + kc * 32 + g * 8);

    f32x4 oacc[2][4] = {};      // [qt][dt]: q=l15, d = dt*16 + g*4 + r
    float m_run[2] = {-1e30f, -1e30f};
    float l_run[2] = {0.0f, 0.0f};

    const u16* Kb = QKV + 2048 + kvh * 64 + g * 8;                 // + row*3072 (+32 for half 1)
    const u16* Vb = VtG + (size_t)(kvh * 64 + l15) * 2048 + g * 4; // + dt*16*2048 + kv

    // ---- softmax for one q-tile: consumes st -> emits pb, updates m/l/oacc ----
    auto softmax = [&](int qt, const f32x4* stq, const f32x4* pd, bf16x4* pbq) {
        float s[4][4];
        float tm = -1e30f;
        #pragma unroll
        for (int j = 0; j < 4; ++j)
            #pragma unroll
            for (int rr = 0; rr < 4; ++rr) {
                s[j][rr] = stq[j][rr] + pd[j][rr];
                tm = fmaxf(tm, s[j][rr]);
            }
        tm = fmaxf(tm, __shfl_xor(tm, 16));
        tm = fmaxf(tm, __shfl_xor(tm, 32));
        if (__any(tm > m_run[qt] + 8.0f)) {        // defer-max
            float m_new = fmaxf(m_run[qt], tm);
            float fac = __expf(m_run[qt] - m_new);
            #pragma unroll
            for (int dt = 0; dt < 4; ++dt) oacc[qt][dt] *= fac;
            l_run[qt] *= fac;
            m_run[qt] = m_new;
        }
        float tsum = 0.0f;
        #pragma unroll
        for (int j = 0; j < 4; ++j)
            #pragma unroll
            for (int rr = 0; rr < 4; ++rr) {
                float p = __expf(s[j][rr] - m_run[qt]);
                tsum += p;
                pbq[j][rr] = (short)f2bf(p);
            }
        tsum += __shfl_xor(tsum, 16);
        tsum += __shfl_xor(tsum, 32);
        l_run[qt] += tsum;
    };

    // ---- main loop: fully-unmasked tiles ----
    for (int t = 0; t < iters - 1; ++t) {
        const int kv0 = t * 64;
        bf16x8 kf[4][2];
        #pragma unroll
        for (int j = 0; j < 4; ++j) {
            const u16* kr = Kb + (size_t)(kv0 + j * 16 + l15) * 3072;
            kf[j][0] = *(const bf16x8*)kr;
            kf[j][1] = *(const bf16x8*)(kr + 32);
        }
        f32x4 st[2][4];
        #pragma unroll
        for (int j = 0; j < 4; ++j) {
            f32x4 z = {};
            st[0][j] = __builtin_amdgcn_mfma_f32_16x16x32_bf16(kf[j][0], qf[0][0], z, 0, 0, 0);
            st[0][j] = __builtin_amdgcn_mfma_f32_16x16x32_bf16(kf[j][1], qf[0][1], st[0][j], 0, 0, 0);
            st[1][j] = __builtin_amdgcn_mfma_f32_16x16x32_bf16(kf[j][0], qf[1][0], z, 0, 0, 0);
            st[1][j] = __builtin_amdgcn_mfma_f32_16x16x32_bf16(kf[j][1], qf[1][1], st[1][j], 0, 0, 0);
        }
        f32x4 pd[4];
        #pragma unroll
        for (int j = 0; j < 4; ++j)
            pd[j] = *(const f32x4*)(padf + kv0 + j * 16 + g * 4);

        bf16x4 pb[2][4];
        softmax(0, st[0], pd, pb[0]);
        softmax(1, st[1], pd, pb[1]);

        #pragma unroll
        for (int dt = 0; dt < 4; ++dt) {
            const u16* vr = Vb + (size_t)(dt * 16) * 2048 + kv0;
            #pragma unroll
            for (int j = 0; j < 4; ++j) {
                bf16x4 vf = *(const bf16x4*)(vr + j * 16);
                oacc[0][dt] = pv_mfma(vf, pb[0][j], oacc[0][dt]);
                oacc[1][dt] = pv_mfma(vf, pb[1][j], oacc[1][dt]);
            }
        }
    }

    // ---- masked tail tile (contains the diagonal for both q-tiles) ----
    {
        const int kv0 = (iters - 1) * 64;
        const int jmaxK = ((q0 + 31 - kv0) >> 4) + 1;   // 2 (even qt32) or 4 (odd)
        bf16x8 kf[4][2];
        #pragma unroll
        for (int j = 0; j < 4; ++j) if (j < jmaxK) {
            const u16* kr = Kb + (size_t)(kv0 + j * 16 + l15) * 3072;
            kf[j][0] = *(const bf16x8*)kr;
            kf[j][1] = *(const bf16x8*)(kr + 32);
        }
        f32x4 st[2][4];
        #pragma unroll
        for (int j = 0; j < 4; ++j) if (j < jmaxK) {
            f32x4 z = {};
            st[0][j] = __builtin_amdgcn_mfma_f32_16x16x32_bf16(kf[j][0], qf[0][0], z, 0, 0, 0);
            st[0][j] = __builtin_amdgcn_mfma_f32_16x16x32_bf16(kf[j][1], qf[0][1], st[0][j], 0, 0, 0);
            st[1][j] = __builtin_amdgcn_mfma_f32_16x16x32_bf16(kf[j][0], qf[1][0], z, 0, 0, 0);
            st[1][j] = __builtin_amdgcn_mfma_f32_16x16x32_bf16(kf[j][1], qf[1][1], st[1][j], 0, 0, 0);
        }
        f32x4 pd[4];
        #pragma unroll
        for (int j = 0; j < 4; ++j) if (j < jmaxK)
            pd[j] = *(const f32x4*)(padf + kv0 + j * 16 + g * 4);

        bf16x4 pb[2][4];
        #pragma unroll
        for (int qt = 0; qt < 2; ++qt) {
            const int q = q0 + qt * 16 + l15;
            float s[4][4];
            float tm = -1e30f;
            #pragma unroll
            for (int j = 0; j < 4; ++j) if (j < jmaxK) {
                #pragma unroll
                for (int rr = 0; rr < 4; ++rr) {
                    int kv = kv0 + j * 16 + g * 4 + rr;
                    float v = st[qt][j][rr] + pd[j][rr];
                    v = (kv > q) ? -INFINITY : v;
                    s[j][rr] = v;
                    tm = fmaxf(tm, v);
                }
            }
            tm = fmaxf(tm, __shfl_xor(tm, 16));
            tm = fmaxf(tm, __shfl_xor(tm, 32));
            if (__any(tm > m_run[qt] + 8.0f)) {
                float m_new = fmaxf(m_run[qt], tm);
                float fac = __expf(m_run[qt] - m_new);
                #pragma unroll
                for (int dt = 0; dt < 4; ++dt) oacc[qt][dt] *= fac;
                l_run[qt] *= fac;
                m_run[qt] = m_new;
            }
            float tsum = 0.0f;
            #pragma unroll
            for (int j = 0; j < 4; ++j) if (j < jmaxK) {
                #pragma unroll
                for (int rr = 0; rr < 4; ++rr) {
                    float p = __expf(s[j][rr] - m_run[qt]);
                    tsum += p;
                    pb[qt][j][rr] = (short)f2bf(p);
                }
            }
            tsum += __shfl_xor(tsum, 16);
            tsum += __shfl_xor(tsum, 32);
            l_run[qt] += tsum;
        }

        #pragma unroll
        for (int dt = 0; dt < 4; ++dt) {
            const u16* vr = Vb + (size_t)(dt * 16) * 2048 + kv0;
            #pragma unroll
            for (int j = 0; j < 4; ++j) if (j < jmaxK) {
                bf16x4 vf = *(const bf16x4*)(vr + j * 16);
                oacc[0][dt] = pv_mfma(vf, pb[0][j], oacc[0][dt]);
                oacc[1][dt] = pv_mfma(vf, pb[1][j], oacc[1][dt]);
            }
        }
    }

    // ---- epilogue (own rows/head only; in-place over Q cols is safe) ----
    #pragma unroll
    for (int qt = 0; qt < 2; ++qt) {
        float il = 1.0f / l_run[qt];
        u16* orow = Ob + (size_t)(q0 + qt * 16 + l15) * 3072 + h * 64;
        #pragma unroll
        for (int dt = 0; dt < 4; ++dt) {
            ushort4 o;
            o.x = f2bf(oacc[qt][dt][0] * il);
            o.y = f2bf(oacc[qt][dt][1] * il);
            o.z = f2bf(oacc[qt][dt][2] * il);
            o.w = f2bf(oacc[qt][dt][3] * il);
            *(ushort4*)(orow + dt * 16 + g * 4) = o;
        }
    }
}

extern "C" void kernel_launch(void* const* d_in, const int* in_sizes, int n_in,
                              void* d_out, int out_size, void* d_ws, size_t ws_size,
                              hipStream_t stream) {
    const float* x    = (const float*)d_in[0];
    const float* cosp = (const float*)d_in[1];
    const float* sinp = (const float*)d_in[2];
    const int*   mask = (const int*)d_in[3];
    const float* Wq   = (const float*)d_in[4];
    const float* Wk   = (const float*)d_in[5];
    const float* Wv   = (const float*)d_in[6];
    const float* Wo   = (const float*)d_in[7];
    float* out = (float*)d_out;

    char* ws = (char*)d_ws;
    u16* xb  = (u16*)ws; ws += (size_t)2048 * 2048 * 2;    // x bf16
    u16* Wt  = (u16*)ws; ws += (size_t)3072 * 2048 * 2;    // [Wq^T; Wk^T; Wv^T] bf16 [3072][2048]
    u16* WoT = (u16*)ws; ws += (size_t)2048 * 2048 * 2;    // Wo^T bf16
    u16* QKV = (u16*)ws; ws += (size_t)2048 * 3072 * 2;    // [Q | K | V] bf16 [2048][3072]
    u16* Vt  = (u16*)ws; ws += (size_t)512 * 2048 * 2;     // V^T bf16 [512][2048]
    float* padf = (float*)ws;                              // 2048 floats

    dim3 tb(32, 8);
    k_cvt<<<4096, 256, 0, stream>>>(x, xb, 2048 * 2048);
    k_tconv<<<dim3(64, 64), tb, 0, stream>>>(Wq, Wt, 2048, 2048);
    k_tconv<<<dim3(16, 64), tb, 0, stream>>>(Wk, Wt + (size_t)2048 * 2048, 2048, 512);
    k_tconv<<<dim3(16, 64), tb, 0, stream>>>(Wv, Wt + (size_t)2560 * 2048, 2048, 512);
    k_tconv<<<dim3(64, 64), tb, 0, stream>>>(Wo, WoT, 2048, 2048);

    // fused QKV projection: [2048][3072] = xb [2048][2048] x Wt^T
    k_gemm<0><<<dim3(24, 16), 512, 0, stream>>>(xb, 2048, Wt, QKV, 2048, 3072, 2048);

    k_rope<<<dim3(5, 2048), 256, 0, stream>>>(QKV, cosp, sinp, mask, padf);
    k_tbf16<<<dim3(16, 64), tb, 0, stream>>>(QKV + 2560, 3072, Vt, 2048, 512);

    k_attn<<<dim3(64, 8), 256, 0, stream>>>(QKV, Vt, padf, QKV);

    // output projection reads attn result from QKV cols 0..2047 (lda=3072)
    k_gemm<1><<<dim3(16, 16), 512, 0, stream>>>(QKV, 3072, WoT, out, 2048, 2048, 2048);
}

// Round 6
// 171.292 us; speedup vs baseline: 1.7385x; 1.7385x over previous
//
#include <hip/hip_runtime.h>
#include <hip/hip_bf16.h>
#include <math.h>

typedef __attribute__((ext_vector_type(4))) float f32x4;
typedef __attribute__((ext_vector_type(8))) short bf16x8;
typedef __attribute__((ext_vector_type(4))) short bf16x4;
typedef unsigned short u16;
typedef unsigned int u32;

// T=2048, D=2048, NH=32, NKV=8, HD=64, G=4

__device__ __forceinline__ float exp2fast(float x) {
    return __builtin_amdgcn_exp2f(x);              // bare v_exp_f32 (base-2)
}
__device__ __forceinline__ u16 f2bf(float f) {
    return __builtin_bit_cast(u16, __float2bfloat16(f));   // native v_cvt on gfx950
}
__device__ __forceinline__ float bf2f(u16 h) {
    return __builtin_bit_cast(float, ((u32)h) << 16);
}

// async global->LDS, 16B per lane; dest is wave-uniform base + lane*16
#define GLL16(gsrc, ldst) __builtin_amdgcn_global_load_lds( \
    (const __attribute__((address_space(1))) u32*)(gsrc),   \
    (__attribute__((address_space(3))) u32*)(ldst), 16, 0, 0)

// ---------------- f32 -> bf16 convert (x) ----------------
__global__ void k_cvt(const float* __restrict__ in, u16* __restrict__ out, int n) {
    int i = blockIdx.x * blockDim.x + threadIdx.x;
    int base = i * 4;
    if (base < n) {
        float4 v = *(const float4*)(in + base);
        ushort4 o;
        o.x = f2bf(v.x); o.y = f2bf(v.y); o.z = f2bf(v.z); o.w = f2bf(v.w);
        *(ushort4*)(out + base) = o;
    }
}

// ------------- transpose + convert: in [R][C] f32 -> out [C][R] bf16 -------------
__global__ void k_tconv(const float* __restrict__ in, u16* __restrict__ out, int R, int C) {
    __shared__ float tile[32][33];
    int c0 = blockIdx.x * 32, r0 = blockIdx.y * 32;
    int tx = threadIdx.x, ty = threadIdx.y;        // (32,8)
    #pragma unroll
    for (int i = 0; i < 4; ++i)
        tile[ty + i * 8][tx] = in[(size_t)(r0 + ty + i * 8) * C + c0 + tx];
    __syncthreads();
    #pragma unroll
    for (int i = 0; i < 4; ++i)
        out[(size_t)(c0 + ty + i * 8) * R + r0 + tx] = f2bf(tile[tx][ty + i * 8]);
}

// ------------- bf16 transpose: in [R][stride, C cols] -> out [C][R] -------------
__global__ void k_tbf16(const u16* __restrict__ in, int inStride, u16* __restrict__ out, int R, int C) {
    __shared__ u16 tile[32][34];
    int c0 = blockIdx.x * 32, r0 = blockIdx.y * 32;
    int tx = threadIdx.x, ty = threadIdx.y;        // (32,8)
    #pragma unroll
    for (int i = 0; i < 4; ++i)
        tile[ty + i * 8][tx] = in[(size_t)(r0 + ty + i * 8) * inStride + c0 + tx];
    __syncthreads();
    #pragma unroll
    for (int i = 0; i < 4; ++i)
        out[(size_t)(c0 + ty + i * 8) * R + r0 + tx] = tile[tx][ty + i * 8];
}

// ------------- RoPE in-place on QKV; Q gets 0.125*log2(e) folded in (exp2-domain
// softmax downstream); fills padf -------------
__global__ void k_rope(u16* QKV,
                       const float* __restrict__ cosp, const float* __restrict__ sinp,
                       const int* __restrict__ maskp, float* __restrict__ padf) {
    int t = blockIdx.y;
    int idx = blockIdx.x * blockDim.x + threadIdx.x;   // 0..1279 ; 40 heads * 32 pairs
    if (blockIdx.x == 0 && threadIdx.x == 0)
        padf[t] = maskp[t] ? 0.0f : -3.4028235e38f;
    int h = idx >> 5;
    int j = idx & 31;
    u16* base = QKV + (size_t)t * 3072 + (h < 32 ? h * 64 : 2048 + (h - 32) * 64);
    float sc = (h < 32) ? 0.18033688f : 1.0f;      // 0.125 * log2(e)
    float q1 = bf2f(base[j]);
    float q2 = bf2f(base[j + 32]);
    float c1 = cosp[t * 64 + j],      s1 = sinp[t * 64 + j];
    float c2 = cosp[t * 64 + j + 32], s2 = sinp[t * 64 + j + 32];
    base[j]      = f2bf((q1 * c1 - q2 * s1) * sc);
    base[j + 32] = f2bf((q2 * c2 + q1 * s2) * sc);
}

// ------------- bf16 GEMM: C[M][N] = A[M][K] * Bt[N][K]^T -------------
// 128x128 tile, BK=32, 512 threads (8 waves: 2 row x 4 col, wave tile 64x32),
// double-buffered LDS, stage-next-before-compute (2-phase), 1 barrier/iter.
template<int OUTF32>
__global__ __launch_bounds__(512) void k_gemm(const u16* __restrict__ A, int lda,
                                              const u16* __restrict__ Bt,
                                              void* __restrict__ Cv,
                                              int M, int N, int K) {
    __shared__ u16 As[2][128 * 32];
    __shared__ u16 Bs[2][128 * 32];
    const int tid = threadIdx.x;
    const int w = tid >> 6, lane = tid & 63;
    const int wr = w & 1, wc = w >> 1;             // wr 0..1 (64 rows), wc 0..3 (32 cols)
    const int g = lane >> 4, l15 = lane & 15;
    const int m0 = blockIdx.y * 128, n0 = blockIdx.x * 128;

    f32x4 acc[4][2] = {};

    const int p = tid;
    const int r = p >> 2, kc = (p & 3) ^ (r & 3);
    const u16* ga = A + (size_t)(m0 + r) * lda + kc * 8;
    const u16* gb = Bt + (size_t)(n0 + r) * K + kc * 8;
    u16* la = &As[0][0] + (size_t)p * 8;
    u16* lb = &Bs[0][0] + (size_t)p * 8;
    const size_t bufoff = 128 * 32;

    GLL16(ga, la);
    GLL16(gb, lb);
    __syncthreads();
    int buf = 0;

    for (int k0 = 0; k0 < K; k0 += 32) {
        int kn = k0 + 32;
        if (kn < K) {                                // prefetch next K-tile into other buf
            GLL16(ga + kn, la + (buf ^ 1) * bufoff);
            GLL16(gb + kn, lb + (buf ^ 1) * bufoff);
        }
        bf16x8 af[4], bfr[2];
        #pragma unroll
        for (int mt = 0; mt < 4; ++mt) {
            int row = wr * 64 + mt * 16 + l15;
            af[mt] = *(const bf16x8*)&As[buf][row * 32 + ((g ^ (row & 3)) << 3)];
        }
        #pragma unroll
        for (int nt = 0; nt < 2; ++nt) {
            int rowb = wc * 32 + nt * 16 + l15;
            bfr[nt] = *(const bf16x8*)&Bs[buf][rowb * 32 + ((g ^ (rowb & 3)) << 3)];
        }
        #pragma unroll
        for (int mt = 0; mt < 4; ++mt)
            #pragma unroll
            for (int nt = 0; nt < 2; ++nt)
                acc[mt][nt] = __builtin_amdgcn_mfma_f32_16x16x32_bf16(af[mt], bfr[nt], acc[mt][nt], 0, 0, 0);
        __syncthreads();
        buf ^= 1;
    }
    #pragma unroll
    for (int mt = 0; mt < 4; ++mt) {
        #pragma unroll
        for (int nt = 0; nt < 2; ++nt) {
            int mrow = m0 + wr * 64 + mt * 16 + g * 4;
            int ncol = n0 + wc * 32 + nt * 16 + l15;
            #pragma unroll
            for (int rr = 0; rr < 4; ++rr) {
                float v = acc[mt][nt][rr];
                if (OUTF32) ((float*)Cv)[(size_t)(mrow + rr) * N + ncol] = v;
                else        ((u16*)Cv)[(size_t)(mrow + rr) * N + ncol] = f2bf(v);
            }
        }
    }
}

// ------------- PV MFMA: prefer 16x16x16 bf16; fallback = zero-padded 16x16x32 -------------
#if defined(__has_builtin)
#if __has_builtin(__builtin_amdgcn_mfma_f32_16x16x16bf16_1k)
#define HAVE_1K 1
#endif
#endif
__device__ __forceinline__ f32x4 pv_mfma(bf16x4 a, bf16x4 b, f32x4 c) {
#ifdef HAVE_1K
    return __builtin_amdgcn_mfma_f32_16x16x16bf16_1k(a, b, c, 0, 0, 0);
#else
    bf16x8 a8 = {a[0], a[1], a[2], a[3], (short)0, (short)0, (short)0, (short)0};
    bf16x8 b8 = {b[0], b[1], b[2], b[3], (short)0, (short)0, (short)0, (short)0};
    return __builtin_amdgcn_mfma_f32_16x16x32_bf16(a8, b8, c, 0, 0, 0);
#endif
}

// ------------- flash attention (R2 LDS structure + load-balance remap + exp2 softmax) ----
// Block = 4 waves = 4 Q-heads of one KV-head, 16 q-rows each (grid 128x8 = 1024 blocks).
// Load balance: CU c receives blocks {c, c+256, c+512, c+768} (same x, y differing by 2);
// qt16 = (kvh>=4) ? x : 127-x makes each CU hold 2 long + 2 short blocks (~const work).
// K,V^T tiles (KVBLK=64) in XOR-swizzled dbuf LDS. Swapped layout (S^T = K*Q^T) keeps
// softmax lane-local; P^T feeds PV B-frag directly. Scores arrive in log2-domain
// (0.125*log2e folded into Q) so softmax uses bare v_exp_f32.
__global__ __launch_bounds__(256) void k_attn(const u16* __restrict__ QKV,
                                              const u16* __restrict__ VtG,
                                              const float* __restrict__ padf,
                                              u16* __restrict__ Ob) {
    __shared__ u16 Ks[2][64 * 64];
    __shared__ u16 Vs[2][64 * 64];
    const int kvh = blockIdx.y;
    const int qt16 = (kvh >= 4) ? (int)blockIdx.x : 127 - (int)blockIdx.x;
    const int tid = threadIdx.x;
    const int w = tid >> 6, lane = tid & 63;
    const int g = lane >> 4, l15 = lane & 15;
    const int h = kvh * 4 + w;
    const int q0 = qt16 * 16;
    const int iters = (qt16 >> 2) + 1;
    const int q = q0 + l15;

    bf16x8 qf0 = *(const bf16x8*)(QKV + (size_t)q * 3072 + h * 64 + g * 8);
    bf16x8 qf1 = *(const bf16x8*)(QKV + (size_t)q * 3072 + h * 64 + 32 + g * 8);

    f32x4 oacc[4] = {};       // oacc[dt][r]: (q=l15 row, d = dt*16 + g*4 + r)
    float m_run = -1e30f, l_run = 0.0f;

    auto stage = [&](int b, int kv0) {
        #pragma unroll
        for (int i = 0; i < 2; ++i) {
            int p = i * 256 + tid;                 // 16B chunk; per-wave contiguous lanes
            int rr = p >> 3, c = p & 7;
            int cs = c ^ (rr & 7);
            GLL16(QKV + (size_t)(kv0 + rr) * 3072 + 2048 + kvh * 64 + cs * 8, &Ks[b][p * 8]);
            GLL16(VtG + (size_t)(kvh * 64 + rr) * 2048 + kv0 + cs * 8, &Vs[b][p * 8]);
        }
    };

    stage(0, 0);
    __syncthreads();
    int buf = 0;

    // ---- main loop: fully-unmasked tiles ----
    for (int t = 0; t < iters - 1; ++t) {
        const int kv0 = t * 64;
        stage(buf ^ 1, kv0 + 64);                  // prefetch in flight during compute

        f32x4 st[4];
        #pragma unroll
        for (int j = 0; j < 4; ++j) {
            int row = j * 16 + l15;
            int rb = row * 64, sw = (row & 7) << 3;
            bf16x8 kf0 = *(const bf16x8*)&Ks[buf][rb + ((g << 3) ^ sw)];
            bf16x8 kf1 = *(const bf16x8*)&Ks[buf][rb + ((32 + (g << 3)) ^ sw)];
            f32x4 z = {};
            st[j] = __builtin_amdgcn_mfma_f32_16x16x32_bf16(kf0, qf0, z, 0, 0, 0);
            st[j] = __builtin_amdgcn_mfma_f32_16x16x32_bf16(kf1, qf1, st[j], 0, 0, 0);
        }

        float s[4][4];
        float tm = -1e30f;
        #pragma unroll
        for (int j = 0; j < 4; ++j) {
            f32x4 pd = *(const f32x4*)(padf + kv0 + j * 16 + g * 4);
            #pragma unroll
            for (int rr = 0; rr < 4; ++rr) {
                s[j][rr] = st[j][rr] + pd[rr];
                tm = fmaxf(tm, s[j][rr]);
            }
        }
        tm = fmaxf(tm, __shfl_xor(tm, 16));
        tm = fmaxf(tm, __shfl_xor(tm, 32));
        if (__any(tm > m_run + 11.5f)) {           // defer-max (log2-domain threshold)
            float m_new = fmaxf(m_run, tm);
            float fac = exp2fast(m_run - m_new);
            #pragma unroll
            for (int dt = 0; dt < 4; ++dt) oacc[dt] *= fac;
            l_run *= fac;
            m_run = m_new;
        }
        float tsum = 0.0f;
        bf16x4 pb[4];
        #pragma unroll
        for (int j = 0; j < 4; ++j)
            #pragma unroll
            for (int rr = 0; rr < 4; ++rr) {
                float pv = exp2fast(s[j][rr] - m_run);
                tsum += pv;
                pb[j][rr] = (short)f2bf(pv);
            }
        tsum += __shfl_xor(tsum, 16);
        tsum += __shfl_xor(tsum, 32);
        l_run += tsum;

        #pragma unroll
        for (int dt = 0; dt < 4; ++dt) {
            int row = dt * 16 + l15;
            int rb = row * 64, sw7 = row & 7;
            #pragma unroll
            for (int j = 0; j < 4; ++j) {
                int chunk = (j * 2 + (g >> 1)) ^ sw7;
                bf16x4 vf = *(const bf16x4*)&Vs[buf][rb + chunk * 8 + (g & 1) * 4];
                oacc[dt] = pv_mfma(vf, pb[j], oacc[dt]);
            }
        }
        __syncthreads();
        buf ^= 1;
    }

    // ---- masked tail tile (diagonal) ----
    {
        const int kv0 = (iters - 1) * 64;
        const int jmax = (qt16 & 3) + 1;           // live 16-col j-tiles in this tile
        f32x4 st[4];
        #pragma unroll
        for (int j = 0; j < 4; ++j) if (j < jmax) {
            int row = j * 16 + l15;
            int rb = row * 64, sw = (row & 7) << 3;
            bf16x8 kf0 = *(const bf16x8*)&Ks[buf][rb + ((g << 3) ^ sw)];
            bf16x8 kf1 = *(const bf16x8*)&Ks[buf][rb + ((32 + (g << 3)) ^ sw)];
            f32x4 z = {};
            st[j] = __builtin_amdgcn_mfma_f32_16x16x32_bf16(kf0, qf0, z, 0, 0, 0);
            st[j] = __builtin_amdgcn_mfma_f32_16x16x32_bf16(kf1, qf1, st[j], 0, 0, 0);
        }
        float s[4][4];
        float tm = -1e30f;
        #pragma unroll
        for (int j = 0; j < 4; ++j) if (j < jmax) {
            f32x4 pd = *(const f32x4*)(padf + kv0 + j * 16 + g * 4);
            #pragma unroll
            for (int rr = 0; rr < 4; ++rr) {
                int kv = kv0 + j * 16 + g * 4 + rr;
                float v = st[j][rr] + pd[rr];
                v = (kv > q) ? -INFINITY : v;
                s[j][rr] = v;
                tm = fmaxf(tm, v);
            }
        }
        tm = fmaxf(tm, __shfl_xor(tm, 16));
        tm = fmaxf(tm, __shfl_xor(tm, 32));
        if (__any(tm > m_run + 11.5f)) {
            float m_new = fmaxf(m_run, tm);
            float fac = exp2fast(m_run - m_new);
            #pragma unroll
            for (int dt = 0; dt < 4; ++dt) oacc[dt] *= fac;
            l_run *= fac;
            m_run = m_new;
        }
        float tsum = 0.0f;
        bf16x4 pb[4];
        #pragma unroll
        for (int j = 0; j < 4; ++j) if (j < jmax) {
            #pragma unroll
            for (int rr = 0; rr < 4; ++rr) {
                float pv = exp2fast(s[j][rr] - m_run);
                tsum += pv;
                pb[j][rr] = (short)f2bf(pv);
            }
        }
        tsum += __shfl_xor(tsum, 16);
        tsum += __shfl_xor(tsum, 32);
        l_run += tsum;

        #pragma unroll
        for (int dt = 0; dt < 4; ++dt) {
            int row = dt * 16 + l15;
            int rb = row * 64, sw7 = row & 7;
            #pragma unroll
            for (int j = 0; j < 4; ++j) if (j < jmax) {
                int chunk = (j * 2 + (g >> 1)) ^ sw7;
                bf16x4 vf = *(const bf16x4*)&Vs[buf][rb + chunk * 8 + (g & 1) * 4];
                oacc[dt] = pv_mfma(vf, pb[j], oacc[dt]);
            }
        }
    }

    // ---- epilogue (own rows/head only; in-place over Q cols is safe) ----
    float il = 1.0f / l_run;
    u16* orow = Ob + (size_t)q * 3072 + h * 64;
    #pragma unroll
    for (int dt = 0; dt < 4; ++dt) {
        ushort4 o;
        o.x = f2bf(oacc[dt][0] * il);
        o.y = f2bf(oacc[dt][1] * il);
        o.z = f2bf(oacc[dt][2] * il);
        o.w = f2bf(oacc[dt][3] * il);
        *(ushort4*)(orow + dt * 16 + g * 4) = o;
    }
}

extern "C" void kernel_launch(void* const* d_in, const int* in_sizes, int n_in,
                              void* d_out, int out_size, void* d_ws, size_t ws_size,
                              hipStream_t stream) {
    const float* x    = (const float*)d_in[0];
    const float* cosp = (const float*)d_in[1];
    const float* sinp = (const float*)d_in[2];
    const int*   mask = (const int*)d_in[3];
    const float* Wq   = (const float*)d_in[4];
    const float* Wk   = (const float*)d_in[5];
    const float* Wv   = (const float*)d_in[6];
    const float* Wo   = (const float*)d_in[7];
    float* out = (float*)d_out;

    char* ws = (char*)d_ws;
    u16* xb  = (u16*)ws; ws += (size_t)2048 * 2048 * 2;    // x bf16
    u16* Wt  = (u16*)ws; ws += (size_t)3072 * 2048 * 2;    // [Wq^T; Wk^T; Wv^T] bf16 [3072][2048]
    u16* WoT = (u16*)ws; ws += (size_t)2048 * 2048 * 2;    // Wo^T bf16
    u16* QKV = (u16*)ws; ws += (size_t)2048 * 3072 * 2;    // [Q | K | V] bf16 [2048][3072]
    u16* Vt  = (u16*)ws; ws += (size_t)512 * 2048 * 2;     // V^T bf16 [512][2048]
    float* padf = (float*)ws;                              // 2048 floats

    dim3 tb(32, 8);
    k_cvt<<<4096, 256, 0, stream>>>(x, xb, 2048 * 2048);
    k_tconv<<<dim3(64, 64), tb, 0, stream>>>(Wq, Wt, 2048, 2048);
    k_tconv<<<dim3(16, 64), tb, 0, stream>>>(Wk, Wt + (size_t)2048 * 2048, 2048, 512);
    k_tconv<<<dim3(16, 64), tb, 0, stream>>>(Wv, Wt + (size_t)2560 * 2048, 2048, 512);
    k_tconv<<<dim3(64, 64), tb, 0, stream>>>(Wo, WoT, 2048, 2048);

    // fused QKV projection: [2048][3072] = xb [2048][2048] x Wt^T
    k_gemm<0><<<dim3(24, 16), 512, 0, stream>>>(xb, 2048, Wt, QKV, 2048, 3072, 2048);

    k_rope<<<dim3(5, 2048), 256, 0, stream>>>(QKV, cosp, sinp, mask, padf);
    k_tbf16<<<dim3(16, 64), tb, 0, stream>>>(QKV + 2560, 3072, Vt, 2048, 512);

    k_attn<<<dim3(128, 8), 256, 0, stream>>>(QKV, Vt, padf, QKV);

    // output projection reads attn result from QKV cols 0..2047 (lda=3072)
    k_gemm<1><<<dim3(16, 16), 512, 0, stream>>>(QKV, 3072, WoT, out, 2048, 2048, 2048);
}